// Round 4
// baseline (349.428 us; speedup 1.0000x reference)
//
#include <hip/hip_runtime.h>
#include <math.h>

// PCNN fused: Conv1d(k=3,pad=1) -> masked piecewise max-pool -> tanh
// MFMA bf16, R4 = R3 + epilogue fix (384-elem combine must loop, block=256).
// Block = (batch b, h-half hb): M=128 (all l), N=128 h. Grid (2048, 2).
// Wave tile M=64 x N=64 (64 AGPR acc) for 3 waves/EU occupancy.
// W pre-packed into MFMA fragment order: each B-load = contiguous 1KB/wave.

#define B_SZ   2048
#define L_SEQ  128
#define C_INCH 150
#define H_OUT  230
#define HPAD   256      // padded h
#define CPAD   160      // padded channels per shift (5 chunks of 32)
#define RS     168      // LDS X row stride in bf16 (336 B, 16B-aligned rows)

typedef __attribute__((ext_vector_type(8))) short short8;   // 8 bf16
typedef __attribute__((ext_vector_type(4))) float float4v;  // mfma acc

static __device__ __forceinline__ unsigned short f2bf(float f) {
    union { float f; unsigned u; } x{f};
    unsigned r = (x.u + 0x7FFFu + ((x.u >> 16) & 1u)) >> 16;  // RNE
    return (unsigned short)r;
}

// Pack W[h][c][k] fp32 -> Wpk in fragment order:
//   kk = k*5 + kc (15 K-chunks of 32), ht = h/16 (16 tiles), lane = q*16 + c15
//   Wpk[((kk*16 + ht)*64 + lane)*8 + e] = bf16(W[h = ht*16+c15][c = kc*32+q*8+e][k])
__global__ void pack_w_kernel(const float* __restrict__ W,
                              unsigned short* __restrict__ Wpk) {
    int t = blockIdx.x * 256 + threadIdx.x;       // < 15360
    int kk   = t >> 10;                           // /1024
    int rem  = t & 1023;
    int ht   = rem >> 6;
    int lane = rem & 63;
    int q    = lane >> 4;
    int c15  = lane & 15;
    int k    = kk / 5;
    int kc   = kk - k * 5;
    int h    = ht * 16 + c15;
    int cb   = kc * 32 + q * 8;
    unsigned short v[8];
    #pragma unroll
    for (int e = 0; e < 8; ++e) {
        int c = cb + e;
        float f = (h < H_OUT && c < C_INCH) ? W[h * 450 + c * 3 + k] : 0.0f;
        v[e] = f2bf(f);
    }
    *(short8*)(Wpk + (size_t)t * 8) = *(short8*)v;
}

__global__ void __launch_bounds__(256, 3)
pcnn_mfma_kernel(const float* __restrict__ Xea, const int* __restrict__ Xmask,
                 const unsigned short* __restrict__ Wpk,
                 const float* __restrict__ bias, float* __restrict__ out) {
    __shared__ __align__(16) unsigned short sX[130 * RS];  // 43680 B
    __shared__ int   sM[L_SEQ];
    __shared__ float sP[2 * 128 * 3];                      // cross-wave partial maxima

    const int b    = blockIdx.x;
    const int hb   = blockIdx.y;               // h-half: 0 or 1
    const int tid  = threadIdx.x;
    const int wv   = tid >> 6;
    const int lane = tid & 63;
    const int q    = lane >> 4;
    const int c15  = lane & 15;
    const int mh   = wv & 1;                   // m-half: l offset 64*mh
    const int nh   = wv >> 1;                  // n-half: h offset 64*nh

    const float* xb = Xea + (size_t)b * (L_SEQ * C_INCH);

    // ---- Stage X[b] fp32 -> bf16 LDS, rows = l+1, halo rows 0 & 129 ----
    for (int t = tid; t < (L_SEQ * C_INCH) / 2; t += 256) {   // 9600 float2s
        int l  = t / 75;
        int c2 = (t - l * 75) * 2;
        const float2 v = *(const float2*)(xb + l * C_INCH + c2);
        unsigned short* p = sX + (l + 1) * RS + c2;
        p[0] = f2bf(v.x);
        p[1] = f2bf(v.y);
    }
    for (int t = tid; t < 2 * RS; t += 256) {                 // halo rows
        int row = (t < RS) ? 0 : 129;
        sX[row * RS + (t % RS)] = 0;
    }
    for (int t = tid; t < 128 * (CPAD - C_INCH); t += 256) {  // channel pad
        int r = t / (CPAD - C_INCH);
        int c = C_INCH + (t - r * (CPAD - C_INCH));
        sX[(r + 1) * RS + c] = 0;
    }
    if (tid < L_SEQ) sM[tid] = Xmask[(size_t)b * L_SEQ + tid];
    __syncthreads();

    // ---- MFMA main loop: 15 K-chunks of 32, no barriers ----
    float4v acc[4][4];
    #pragma unroll
    for (int mi = 0; mi < 4; ++mi)
        #pragma unroll
        for (int nj = 0; nj < 4; ++nj)
            acc[mi][nj] = (float4v){0.f, 0.f, 0.f, 0.f};

    // B pointer: fragment-ordered, contiguous 1KB per wave-load
    const unsigned short* wp =
        Wpk + ((size_t)((hb * 8 + nh * 4)) * 64 + lane) * 8;
    const int aoff0 = (mh * 64 + c15) * RS + q * 8;

    for (int k = 0; k < 3; ++k) {
        #pragma unroll
        for (int kc = 0; kc < 5; ++kc) {
            short8 a[4];
            #pragma unroll
            for (int mi = 0; mi < 4; ++mi)
                a[mi] = *(const short8*)(sX + aoff0 + (mi * 16 + k) * RS + kc * 32);
            short8 bf[4];
            #pragma unroll
            for (int nj = 0; nj < 4; ++nj)
                bf[nj] = *(const short8*)(wp + nj * 512);
            #pragma unroll
            for (int mi = 0; mi < 4; ++mi)
                #pragma unroll
                for (int nj = 0; nj < 4; ++nj)
                    acc[mi][nj] = __builtin_amdgcn_mfma_f32_16x16x32_bf16(
                        a[mi], bf[nj], acc[mi][nj], 0, 0, 0);
            wp += 16 * 64 * 8;   // next kk chunk
        }
    }

    // ---- Epilogue: bias + masked piecewise max over this wave's 64 l ----
    // C/D layout: col(h) = c15, row(l within frag) = q*4 + r
    #pragma unroll
    for (int nj = 0; nj < 4; ++nj) {
        const int h = hb * 128 + nh * 64 + nj * 16 + c15;
        const float bh = (h < H_OUT) ? bias[h] : 0.0f;
        float p0 = 0.f, p1 = 0.f, p2 = 0.f;
        #pragma unroll
        for (int mi = 0; mi < 4; ++mi) {
            #pragma unroll
            for (int r = 0; r < 4; ++r) {
                const int l = mh * 64 + mi * 16 + q * 4 + r;
                const int mv = sM[l];
                const float y = acc[mi][nj][r] + bh;
                p0 = fmaxf(p0, (mv == 1) ? y : 0.0f);
                p1 = fmaxf(p1, (mv == 2) ? y : 0.0f);
                p2 = fmaxf(p2, (mv == 3) ? y : 0.0f);
            }
        }
        p0 = fmaxf(p0, __shfl_xor(p0, 16, 64));
        p1 = fmaxf(p1, __shfl_xor(p1, 16, 64));
        p2 = fmaxf(p2, __shfl_xor(p2, 16, 64));
        p0 = fmaxf(p0, __shfl_xor(p0, 32, 64));
        p1 = fmaxf(p1, __shfl_xor(p1, 32, 64));
        p2 = fmaxf(p2, __shfl_xor(p2, 32, 64));
        if (q == 0) {
            const int hl = nh * 64 + nj * 16 + c15;    // 0..127
            float* d = sP + (mh * 128 + hl) * 3;
            d[0] = p0; d[1] = p1; d[2] = p2;
        }
    }
    __syncthreads();

    // Combine the two m-halves, tanh, store. 384 outputs, 256 threads -> loop!
    for (int t = tid; t < 384; t += 256) {
        const int hl = t / 3;
        const int p  = t - hl * 3;
        const int h  = hb * 128 + hl;
        if (h < H_OUT) {
            const float v = fmaxf(sP[hl * 3 + p], sP[(128 + hl) * 3 + p]);
            out[(size_t)b * (3 * H_OUT) + h * 3 + p] = tanhf(v);
        }
    }
}

extern "C" void kernel_launch(void* const* d_in, const int* in_sizes, int n_in,
                              void* d_out, int out_size, void* d_ws, size_t ws_size,
                              hipStream_t stream) {
    const float* Xea   = (const float*)d_in[0];   // [2048,128,150] f32
    const int*   Xmask = (const int*)d_in[1];     // [2048,128] i32
    const float* W     = (const float*)d_in[2];   // [230,150,3] f32
    const float* bias  = (const float*)d_in[3];   // [230] f32
    float* out = (float*)d_out;                   // [2048,690] f32
    unsigned short* Wpk = (unsigned short*)d_ws;  // 15*16*64*8*2 = 245760 B

    pack_w_kernel<<<60, 256, 0, stream>>>(W, Wpk);
    dim3 grid(B_SZ, 2);
    pcnn_mfma_kernel<<<grid, 256, 0, stream>>>(Xea, Xmask, Wpk, bias, out);
}

// Round 5
// 335.062 us; speedup vs baseline: 1.0429x; 1.0429x over previous
//
#include <hip/hip_runtime.h>
#include <math.h>

// PCNN fused: Conv1d(k=3,pad=1) -> masked piecewise max-pool -> tanh
// R5: pre-converted bf16 X + global_load_lds staging, 4 blocks/CU
//     (LDS<=40960, regs<=128), B double-buffer, selector-add epilogue,
//     deferred bias, fast tanh. Fallback to in-kernel convert if ws small.

#define B_SZ   2048
#define L_SEQ  128
#define C_INCH 150
#define H_OUT  230
#define CPAD   160      // padded channels per shift (5 chunks of 32)
#define RS     152      // row stride in bf16 (304 B; stride%32dw=12 -> 2-way free)
#define NROW   129      // rows l=-1..127; l=128 halo remapped to row 0 (both zero)
#define XB_STR (NROW * RS)   // 19608 bf16 per batch
#define WPK_BYTES (15 * 16 * 64 * 8 * 2)  // 245760

typedef __attribute__((ext_vector_type(8))) short short8;   // 8 bf16
typedef __attribute__((ext_vector_type(4))) float float4v;  // mfma acc

static __device__ __forceinline__ unsigned short f2bf(float f) {
    union { float f; unsigned u; } x{f};
    unsigned r = (x.u + 0x7FFFu + ((x.u >> 16) & 1u)) >> 16;  // RNE
    return (unsigned short)r;
}

static __device__ __forceinline__ float tanh_fast_pos(float v) {
    // v >= 0; tanh(v) = 1 - 2/(exp(2v)+1). exp overflow -> 1.0, v=0 -> 0.
    float e = __expf(2.0f * v);
    return 1.0f - 2.0f / (e + 1.0f);
}

static __device__ __forceinline__ void async16(const void* g, void* l) {
    __builtin_amdgcn_global_load_lds(
        (const __attribute__((address_space(1))) unsigned int*)g,
        (__attribute__((address_space(3))) unsigned int*)l, 16, 0, 0);
}

// Pack W[h][c][k] fp32 -> Wpk fragment order (verified R4):
//   kk = k*5+kc, ht = h/16, lane = q*16+c15
//   Wpk[((kk*16+ht)*64+lane)*8 + e] = bf16(W[ht*16+c15][kc*32+q*8+e][k])
__global__ void pack_w_kernel(const float* __restrict__ W,
                              unsigned short* __restrict__ Wpk) {
    int t = blockIdx.x * 256 + threadIdx.x;       // < 15360
    int kk   = t >> 10;
    int rem  = t & 1023;
    int ht   = rem >> 6;
    int lane = rem & 63;
    int q    = lane >> 4;
    int c15  = lane & 15;
    int k    = kk / 5;
    int kc   = kk - k * 5;
    int h    = ht * 16 + c15;
    int cb   = kc * 32 + q * 8;
    unsigned short v[8];
    #pragma unroll
    for (int e = 0; e < 8; ++e) {
        int c = cb + e;
        float f = (h < H_OUT && c < C_INCH) ? W[h * 450 + c * 3 + k] : 0.0f;
        v[e] = f2bf(f);
    }
    *(short8*)(Wpk + (size_t)t * 8) = *(short8*)v;
}

// X fp32 [b][l][c] -> Xbf [b][row=l+1][RS] bf16, row0 = zeros (l=-1 and l=128
// halo), cols 150..151 zero. One block per b.
__global__ void convert_x_kernel(const float* __restrict__ Xea,
                                 unsigned short* __restrict__ Xbf) {
    const int b   = blockIdx.x;
    const int tid = threadIdx.x;
    const float* xb = Xea + (size_t)b * (L_SEQ * C_INCH);
    unsigned short* xo = Xbf + (size_t)b * XB_STR;
    for (int t = tid; t < (L_SEQ * C_INCH) / 2; t += 256) {   // 9600 float2s
        int l  = t / 75;
        int c2 = (t - l * 75) * 2;
        const float2 v = *(const float2*)(xb + l * C_INCH + c2);
        ushort2 w;
        w.x = f2bf(v.x);
        w.y = f2bf(v.y);
        *(ushort2*)(xo + (l + 1) * RS + c2) = w;
    }
    if (tid < RS) xo[tid] = 0;                       // row 0 (halo)
    {   // pad cols 150,151 for rows 1..128 : exactly 256 writes
        int r = tid >> 1, c = C_INCH + (tid & 1);
        xo[(r + 1) * RS + c] = 0;
    }
}

__global__ void __launch_bounds__(256, 4)
pcnn_mfma2(const float* __restrict__ Xea, const unsigned short* __restrict__ Xbf,
           const int* __restrict__ Xmask, const unsigned short* __restrict__ Wpk,
           const float* __restrict__ bias, float* __restrict__ out, int use_pre) {
    __shared__ __align__(16) unsigned short sX[NROW * RS];   // 39216 B
    __shared__ __align__(16) float sSel[L_SEQ * 3];          // 1536 B -> 40752 total

    const int b    = blockIdx.x;
    const int hb   = blockIdx.y;
    const int tid  = threadIdx.x;
    const int wv   = tid >> 6;
    const int lane = tid & 63;
    const int q    = lane >> 4;
    const int c15  = lane & 15;
    const int mh   = wv & 1;          // m-half: l offset 64*mh
    const int nh   = wv >> 1;         // n-half: h offset 64*nh

    // mask -> piece selectors {0, -1e30}
    if (tid < L_SEQ) {
        int mv = Xmask[(size_t)b * L_SEQ + tid];
        sSel[tid * 3 + 0] = (mv == 1) ? 0.0f : -1e30f;
        sSel[tid * 3 + 1] = (mv == 2) ? 0.0f : -1e30f;
        sSel[tid * 3 + 2] = (mv == 3) ? 0.0f : -1e30f;
    }

    if (use_pre) {
        // async DMA: 39216 B = 2451 x16B; 9 full rounds + 147 tail
        const unsigned short* src = Xbf + (size_t)b * XB_STR;
        #pragma unroll
        for (int it = 0; it < 9; ++it) {
            const int base = it * 256 + wv * 64;             // wave-uniform
            async16(src + (size_t)(base + lane) * 8, sX + (size_t)base * 8);
        }
        if (tid < 147) {
            const int idx = 9 * 256 + tid;
            *(short8*)(sX + (size_t)idx * 8) = *(const short8*)(src + (size_t)idx * 8);
        }
    } else {
        const float* xb = Xea + (size_t)b * (L_SEQ * C_INCH);
        for (int t = tid; t < (L_SEQ * C_INCH) / 2; t += 256) {
            int l  = t / 75;
            int c2 = (t - l * 75) * 2;
            const float2 v = *(const float2*)(xb + l * C_INCH + c2);
            unsigned short* p = sX + (l + 1) * RS + c2;
            p[0] = f2bf(v.x);
            p[1] = f2bf(v.y);
        }
        if (tid < RS) sX[tid] = 0;                           // row 0
        {   int r = tid >> 1, c = C_INCH + (tid & 1);        // pad cols
            sX[(r + 1) * RS + c] = 0;
        }
    }
    __syncthreads();   // drains vmcnt (global_load_lds) + lgkm

    // ---- MFMA: 15 K-chunks of 32, B double-buffered from L2 ----
    float4v acc[4][4];
    #pragma unroll
    for (int mi = 0; mi < 4; ++mi)
        #pragma unroll
        for (int nj = 0; nj < 4; ++nj)
            acc[mi][nj] = (float4v){0.f, 0.f, 0.f, 0.f};

    const unsigned short* wp = Wpk + ((size_t)(hb * 8 + nh * 4) * 64 + lane) * 8;
    const unsigned short* a0p = sX + (mh * 64 + c15) * RS + q * 8;
    // l=128 halo: row mh*64+c15+mi*16+k == 129 only at (mh=1,mi=3,c15=15,k=2);
    // remap to row 0 (zeros). Divergent LDS pointer is fine.
    const unsigned short* a3p2 = (mh == 1 && c15 == 15) ? (a0p - 129 * RS) : a0p;

    short8 bc[4], bn[4];
    #pragma unroll
    for (int nj = 0; nj < 4; ++nj)
        bc[nj] = *(const short8*)(wp + nj * 512);

    #pragma unroll
    for (int kk = 0; kk < 15; ++kk) {
        const int k  = kk / 5;
        const int kc = kk - k * 5;
        if (kk < 14) {
            #pragma unroll
            for (int nj = 0; nj < 4; ++nj)
                bn[nj] = *(const short8*)(wp + (kk + 1) * 8192 + nj * 512);
        }
        short8 a[4];
        #pragma unroll
        for (int mi = 0; mi < 4; ++mi) {
            const unsigned short* base = (mi == 3 && k == 2) ? a3p2 : a0p;
            a[mi] = *(const short8*)(base + (mi * 16 + k) * RS + kc * 32);
        }
        #pragma unroll
        for (int mi = 0; mi < 4; ++mi)
            #pragma unroll
            for (int nj = 0; nj < 4; ++nj)
                acc[mi][nj] = __builtin_amdgcn_mfma_f32_16x16x32_bf16(
                    a[mi], bc[nj], acc[mi][nj], 0, 0, 0);
        #pragma unroll
        for (int nj = 0; nj < 4; ++nj)
            bc[nj] = bn[nj];
    }

    // ---- Epilogue: selector-add masked max (bias deferred) ----
    // C/D layout: col(h)=c15, row(l in frag)=q*4+r
    float pz[4][3];
    #pragma unroll
    for (int nj = 0; nj < 4; ++nj)
        #pragma unroll
        for (int p = 0; p < 3; ++p) pz[nj][p] = -1e30f;

    #pragma unroll
    for (int mi = 0; mi < 4; ++mi) {
        const int l0 = mh * 64 + mi * 16 + q * 4;            // mult of 4
        const float4v* sp = (const float4v*)(sSel + l0 * 3); // 48B, 16B-aligned
        const float4v s0 = sp[0], s1 = sp[1], s2 = sp[2];
        const float sl[12] = {s0.x, s0.y, s0.z, s0.w, s1.x, s1.y,
                              s1.z, s1.w, s2.x, s2.y, s2.z, s2.w};
        #pragma unroll
        for (int nj = 0; nj < 4; ++nj)
            #pragma unroll
            for (int r = 0; r < 4; ++r) {
                const float y = acc[mi][nj][r];
                pz[nj][0] = fmaxf(pz[nj][0], y + sl[r * 3 + 0]);
                pz[nj][1] = fmaxf(pz[nj][1], y + sl[r * 3 + 1]);
                pz[nj][2] = fmaxf(pz[nj][2], y + sl[r * 3 + 2]);
            }
    }

    __syncthreads();   // all sX reads done -> safe to alias sP onto sX
    float* sP = (float*)sX;

    #pragma unroll
    for (int nj = 0; nj < 4; ++nj) {
        float p0 = pz[nj][0], p1 = pz[nj][1], p2 = pz[nj][2];
        p0 = fmaxf(p0, __shfl_xor(p0, 16, 64));
        p1 = fmaxf(p1, __shfl_xor(p1, 16, 64));
        p2 = fmaxf(p2, __shfl_xor(p2, 16, 64));
        p0 = fmaxf(p0, __shfl_xor(p0, 32, 64));
        p1 = fmaxf(p1, __shfl_xor(p1, 32, 64));
        p2 = fmaxf(p2, __shfl_xor(p2, 32, 64));
        if (q == 0) {
            const int hl = nh * 64 + nj * 16 + c15;          // 0..127
            float* d = sP + (mh * 128 + hl) * 3;
            d[0] = p0; d[1] = p1; d[2] = p2;
        }
    }
    __syncthreads();

    // Combine m-halves, add bias, clamp 0, tanh, store
    for (int t = tid; t < 384; t += 256) {
        const int hl = t / 3;
        const int p  = t - hl * 3;
        const int h  = hb * 128 + hl;
        if (h < H_OUT) {
            float v = fmaxf(sP[hl * 3 + p], sP[(128 + hl) * 3 + p]);
            v = fmaxf(0.0f, v + bias[h]);
            out[(size_t)b * (3 * H_OUT) + h * 3 + p] = tanh_fast_pos(v);
        }
    }
}

extern "C" void kernel_launch(void* const* d_in, const int* in_sizes, int n_in,
                              void* d_out, int out_size, void* d_ws, size_t ws_size,
                              hipStream_t stream) {
    const float* Xea   = (const float*)d_in[0];   // [2048,128,150] f32
    const int*   Xmask = (const int*)d_in[1];     // [2048,128] i32
    const float* W     = (const float*)d_in[2];   // [230,150,3] f32
    const float* bias  = (const float*)d_in[3];   // [230] f32
    float* out = (float*)d_out;                   // [2048,690] f32

    unsigned short* Wpk = (unsigned short*)d_ws;
    unsigned short* Xbf = (unsigned short*)((char*)d_ws + WPK_BYTES);
    const size_t need = (size_t)WPK_BYTES + (size_t)B_SZ * XB_STR * 2;
    const int use_pre = (ws_size >= need) ? 1 : 0;

    pack_w_kernel<<<60, 256, 0, stream>>>(W, Wpk);
    if (use_pre)
        convert_x_kernel<<<B_SZ, 256, 0, stream>>>(Xea, Xbf);
    dim3 grid(B_SZ, 2);
    pcnn_mfma2<<<grid, 256, 0, stream>>>(Xea, Xbf, Xmask, Wpk, bias, out, use_pre);
}

// Round 6
// 317.042 us; speedup vs baseline: 1.1022x; 1.0568x over previous
//
#include <hip/hip_runtime.h>
#include <math.h>

// PCNN fused: Conv1d(k=3,pad=1) -> masked piecewise max-pool -> tanh
// R6: vectorized convert (short8/thread, 16B stores), GEMM split into
//     PRE (async-DMA staging) / FB (in-kernel convert) instantiations,
//     DMA issued first. Everything else as verified in R5.

#define B_SZ   2048
#define L_SEQ  128
#define C_INCH 150
#define H_OUT  230
#define RS     152      // row stride in bf16 (304 B); 152 = 19*8 -> rows tile into short8
#define NROW   129      // rows l=-1..127; l=128 halo remapped to row 0 (both zero)
#define XB_STR (NROW * RS)   // 19608 bf16 per batch
#define NS8    2451          // short8s per batch = XB_STR/8
#define WPK_BYTES (15 * 16 * 64 * 8 * 2)  // 245760

typedef __attribute__((ext_vector_type(8))) short short8;   // 8 bf16
typedef __attribute__((ext_vector_type(4))) float float4v;  // mfma acc

static __device__ __forceinline__ unsigned short f2bf(float f) {
    union { float f; unsigned u; } x{f};
    unsigned r = (x.u + 0x7FFFu + ((x.u >> 16) & 1u)) >> 16;  // RNE
    return (unsigned short)r;
}

static __device__ __forceinline__ float tanh_fast_pos(float v) {
    float e = __expf(2.0f * v);
    return 1.0f - 2.0f / (e + 1.0f);
}

static __device__ __forceinline__ void async16(const void* g, void* l) {
    __builtin_amdgcn_global_load_lds(
        (const __attribute__((address_space(1))) unsigned int*)g,
        (__attribute__((address_space(3))) unsigned int*)l, 16, 0, 0);
}

// Pack W[h][c][k] fp32 -> Wpk fragment order (verified R4/R5):
//   kk = k*5+kc, ht = h/16, lane = q*16+c15
//   Wpk[((kk*16+ht)*64+lane)*8 + e] = bf16(W[ht*16+c15][kc*32+q*8+e][k])
__global__ void pack_w_kernel(const float* __restrict__ W,
                              unsigned short* __restrict__ Wpk) {
    int t = blockIdx.x * 256 + threadIdx.x;       // < 15360
    int kk   = t >> 10;
    int rem  = t & 1023;
    int ht   = rem >> 6;
    int lane = rem & 63;
    int q    = lane >> 4;
    int c15  = lane & 15;
    int k    = kk / 5;
    int kc   = kk - k * 5;
    int h    = ht * 16 + c15;
    int cb   = kc * 32 + q * 8;
    unsigned short v[8];
    #pragma unroll
    for (int e = 0; e < 8; ++e) {
        int c = cb + e;
        float f = (h < H_OUT && c < C_INCH) ? W[h * 450 + c * 3 + k] : 0.0f;
        v[e] = f2bf(f);
    }
    *(short8*)(Wpk + (size_t)t * 8) = *(short8*)v;
}

// X fp32 [b][l][c] -> Xbf [b][row][RS] bf16; row0 = zeros (halo), cols 150..151
// zero. One short8 (16B store) per thread; 4x float2 (8B, aligned) loads.
__global__ void __launch_bounds__(256)
convert_x_kernel(const float* __restrict__ Xea, unsigned short* __restrict__ Xbf) {
    const int b   = blockIdx.y;
    const int idx = blockIdx.x * 256 + threadIdx.x;   // short8 index within b
    if (idx >= NS8) return;
    const int row = idx / 19;            // 0..128 (const divisor -> magic mul)
    const int j   = idx - row * 19;      // 0..18
    unsigned short v[8] = {0, 0, 0, 0, 0, 0, 0, 0};
    if (row > 0) {
        const float* src = Xea + (size_t)b * (L_SEQ * C_INCH)
                         + (row - 1) * C_INCH + j * 8;
        const int nvalid = (j == 18) ? 6 : 8;   // j=18 covers cols 144..151
        #pragma unroll
        for (int e = 0; e < 8; e += 2) {
            if (e < nvalid) {
                const float2 f = *(const float2*)(src + e);   // 8B-aligned
                v[e]     = f2bf(f.x);
                v[e + 1] = f2bf(f.y);
            }
        }
    }
    *(short8*)(Xbf + (size_t)b * XB_STR + (size_t)idx * 8) = *(short8*)v;
}

template <bool PRE>
__global__ void __launch_bounds__(256, 4)
pcnn_mfma(const float* __restrict__ Xea, const unsigned short* __restrict__ Xbf,
          const int* __restrict__ Xmask, const unsigned short* __restrict__ Wpk,
          const float* __restrict__ bias, float* __restrict__ out) {
    __shared__ __align__(16) unsigned short sX[NROW * RS];   // 39216 B
    __shared__ __align__(16) float sSel[L_SEQ * 3];          // 1536 B

    const int b    = blockIdx.x;
    const int hb   = blockIdx.y;
    const int tid  = threadIdx.x;
    const int wv   = tid >> 6;
    const int lane = tid & 63;
    const int q    = lane >> 4;
    const int c15  = lane & 15;
    const int mh   = wv & 1;          // m-half: l offset 64*mh
    const int nh   = wv >> 1;         // n-half: h offset 64*nh

    if (PRE) {
        // async DMA first: 2451 short8; 9 full wave rounds + 147 tail
        const unsigned short* src = Xbf + (size_t)b * XB_STR;
        #pragma unroll
        for (int it = 0; it < 9; ++it) {
            const int base = it * 256 + wv * 64;             // wave-uniform
            async16(src + (size_t)(base + lane) * 8, sX + (size_t)base * 8);
        }
        if (tid < NS8 - 9 * 256) {
            const int idx = 9 * 256 + tid;
            *(short8*)(sX + (size_t)idx * 8) = *(const short8*)(src + (size_t)idx * 8);
        }
    } else {
        const float* xb = Xea + (size_t)b * (L_SEQ * C_INCH);
        for (int t = tid; t < (L_SEQ * C_INCH) / 2; t += 256) {
            int l  = t / 75;
            int c2 = (t - l * 75) * 2;
            const float2 v = *(const float2*)(xb + l * C_INCH + c2);
            unsigned short* p = sX + (l + 1) * RS + c2;
            p[0] = f2bf(v.x);
            p[1] = f2bf(v.y);
        }
        if (tid < RS) sX[tid] = 0;                           // row 0 (halo)
        {   int r = tid >> 1, c = C_INCH + (tid & 1);        // pad cols
            sX[(r + 1) * RS + c] = 0;
        }
    }

    // mask -> piece selectors {0, -1e30}
    if (tid < L_SEQ) {
        int mv = Xmask[(size_t)b * L_SEQ + tid];
        sSel[tid * 3 + 0] = (mv == 1) ? 0.0f : -1e30f;
        sSel[tid * 3 + 1] = (mv == 2) ? 0.0f : -1e30f;
        sSel[tid * 3 + 2] = (mv == 3) ? 0.0f : -1e30f;
    }
    __syncthreads();   // drains vmcnt (global_load_lds) + lgkm

    // ---- MFMA: 15 K-chunks of 32, B double-buffered from L2 ----
    float4v acc[4][4];
    #pragma unroll
    for (int mi = 0; mi < 4; ++mi)
        #pragma unroll
        for (int nj = 0; nj < 4; ++nj)
            acc[mi][nj] = (float4v){0.f, 0.f, 0.f, 0.f};

    const unsigned short* wp = Wpk + ((size_t)(hb * 8 + nh * 4) * 64 + lane) * 8;
    const unsigned short* a0p = sX + (mh * 64 + c15) * RS + q * 8;
    // l=128 halo: row mh*64+c15+mi*16+k == 129 only at (mh=1,mi=3,c15=15,k=2);
    // remap to row 0 (zeros).
    const unsigned short* a3p2 = (mh == 1 && c15 == 15) ? (a0p - 129 * RS) : a0p;

    short8 bc[4], bn[4];
    #pragma unroll
    for (int nj = 0; nj < 4; ++nj)
        bc[nj] = *(const short8*)(wp + nj * 512);

    #pragma unroll
    for (int kk = 0; kk < 15; ++kk) {
        const int k  = kk / 5;
        const int kc = kk - k * 5;
        if (kk < 14) {
            #pragma unroll
            for (int nj = 0; nj < 4; ++nj)
                bn[nj] = *(const short8*)(wp + (kk + 1) * 8192 + nj * 512);
        }
        short8 a[4];
        #pragma unroll
        for (int mi = 0; mi < 4; ++mi) {
            const unsigned short* base = (mi == 3 && k == 2) ? a3p2 : a0p;
            a[mi] = *(const short8*)(base + (mi * 16 + k) * RS + kc * 32);
        }
        #pragma unroll
        for (int mi = 0; mi < 4; ++mi)
            #pragma unroll
            for (int nj = 0; nj < 4; ++nj)
                acc[mi][nj] = __builtin_amdgcn_mfma_f32_16x16x32_bf16(
                    a[mi], bc[nj], acc[mi][nj], 0, 0, 0);
        #pragma unroll
        for (int nj = 0; nj < 4; ++nj)
            bc[nj] = bn[nj];
    }

    // ---- Epilogue: selector-add masked max (bias deferred) ----
    // C/D layout: col(h)=c15, row(l in frag)=q*4+r
    float pz[4][3];
    #pragma unroll
    for (int nj = 0; nj < 4; ++nj)
        #pragma unroll
        for (int p = 0; p < 3; ++p) pz[nj][p] = -1e30f;

    #pragma unroll
    for (int mi = 0; mi < 4; ++mi) {
        const int l0 = mh * 64 + mi * 16 + q * 4;            // mult of 4
        const float4v* sp = (const float4v*)(sSel + l0 * 3); // 48B, 16B-aligned
        const float4v s0 = sp[0], s1 = sp[1], s2 = sp[2];
        const float sl[12] = {s0.x, s0.y, s0.z, s0.w, s1.x, s1.y,
                              s1.z, s1.w, s2.x, s2.y, s2.z, s2.w};
        #pragma unroll
        for (int nj = 0; nj < 4; ++nj)
            #pragma unroll
            for (int r = 0; r < 4; ++r) {
                const float y = acc[mi][nj][r];
                pz[nj][0] = fmaxf(pz[nj][0], y + sl[r * 3 + 0]);
                pz[nj][1] = fmaxf(pz[nj][1], y + sl[r * 3 + 1]);
                pz[nj][2] = fmaxf(pz[nj][2], y + sl[r * 3 + 2]);
            }
    }

    __syncthreads();   // all sX reads done -> alias partials onto sX
    float* sP = (float*)sX;

    #pragma unroll
    for (int nj = 0; nj < 4; ++nj) {
        float p0 = pz[nj][0], p1 = pz[nj][1], p2 = pz[nj][2];
        p0 = fmaxf(p0, __shfl_xor(p0, 16, 64));
        p1 = fmaxf(p1, __shfl_xor(p1, 16, 64));
        p2 = fmaxf(p2, __shfl_xor(p2, 16, 64));
        p0 = fmaxf(p0, __shfl_xor(p0, 32, 64));
        p1 = fmaxf(p1, __shfl_xor(p1, 32, 64));
        p2 = fmaxf(p2, __shfl_xor(p2, 32, 64));
        if (q == 0) {
            const int hl = nh * 64 + nj * 16 + c15;          // 0..127
            float* d = sP + (mh * 128 + hl) * 3;
            d[0] = p0; d[1] = p1; d[2] = p2;
        }
    }
    __syncthreads();

    // Combine m-halves, add bias, clamp 0, tanh, store
    for (int t = tid; t < 384; t += 256) {
        const int hl = t / 3;
        const int p  = t - hl * 3;
        const int h  = hb * 128 + hl;
        if (h < H_OUT) {
            float v = fmaxf(sP[hl * 3 + p], sP[(128 + hl) * 3 + p]);
            v = fmaxf(0.0f, v + bias[h]);
            out[(size_t)b * (3 * H_OUT) + h * 3 + p] = tanh_fast_pos(v);
        }
    }
}

extern "C" void kernel_launch(void* const* d_in, const int* in_sizes, int n_in,
                              void* d_out, int out_size, void* d_ws, size_t ws_size,
                              hipStream_t stream) {
    const float* Xea   = (const float*)d_in[0];   // [2048,128,150] f32
    const int*   Xmask = (const int*)d_in[1];     // [2048,128] i32
    const float* W     = (const float*)d_in[2];   // [230,150,3] f32
    const float* bias  = (const float*)d_in[3];   // [230] f32
    float* out = (float*)d_out;                   // [2048,690] f32

    unsigned short* Wpk = (unsigned short*)d_ws;
    unsigned short* Xbf = (unsigned short*)((char*)d_ws + WPK_BYTES);
    const size_t need = (size_t)WPK_BYTES + (size_t)B_SZ * XB_STR * 2;
    const int use_pre = (ws_size >= need) ? 1 : 0;

    pack_w_kernel<<<60, 256, 0, stream>>>(W, Wpk);
    dim3 grid(B_SZ, 2);
    if (use_pre) {
        dim3 cgrid((NS8 + 255) / 256, B_SZ);
        convert_x_kernel<<<cgrid, 256, 0, stream>>>(Xea, Xbf);
        pcnn_mfma<true><<<grid, 256, 0, stream>>>(Xea, Xbf, Xmask, Wpk, bias, out);
    } else {
        pcnn_mfma<false><<<grid, 256, 0, stream>>>(Xea, Xbf, Xmask, Wpk, bias, out);
    }
}

// Round 7
// 299.993 us; speedup vs baseline: 1.1648x; 1.0568x over previous
//
#include <hip/hip_runtime.h>
#include <hip/hip_bf16.h>
#include <math.h>

// PCNN fused: Conv1d(k=3,pad=1) -> masked piecewise max-pool -> tanh
// R7: single fused GEMM (no convert_x / Xbf): staging converts fp32->bf16
//     in-kernel via packed v_cvt_pk_bf16_f32, one short8 ds_write_b128 per
//     thread-iter. Everything else identical to verified R6 PRE path.

#define B_SZ   2048
#define L_SEQ  128
#define C_INCH 150
#define H_OUT  230
#define RS     152      // row stride in bf16 (304 B); 152 = 19*8
#define NROW   129      // rows l=-1..127; l=128 halo remapped to row 0 (both zero)
#define NS8    2451     // short8s per block tile = NROW*RS/8

typedef __attribute__((ext_vector_type(8))) short short8;   // 8 bf16
typedef __attribute__((ext_vector_type(4))) float float4v;  // mfma acc

static __device__ __forceinline__ unsigned short f2bf(float f) {
    union { float f; unsigned u; } x{f};
    unsigned r = (x.u + 0x7FFFu + ((x.u >> 16) & 1u)) >> 16;  // RNE
    return (unsigned short)r;
}

static __device__ __forceinline__ unsigned cvt2(float2 f) {
    __hip_bfloat162 h = __float22bfloat162_rn(f);   // v_cvt_pk_bf16_f32 on gfx950
    union { __hip_bfloat162 h; unsigned u; } c{h};
    return c.u;
}

static __device__ __forceinline__ float tanh_fast_pos(float v) {
    float e = __expf(2.0f * v);
    return 1.0f - 2.0f / (e + 1.0f);
}

// Pack W[h][c][k] fp32 -> Wpk fragment order (verified R4-R6):
//   kk = k*5+kc, ht = h/16, lane = q*16+c15
//   Wpk[((kk*16+ht)*64+lane)*8 + e] = bf16(W[ht*16+c15][kc*32+q*8+e][k])
__global__ void pack_w_kernel(const float* __restrict__ W,
                              unsigned short* __restrict__ Wpk) {
    int t = blockIdx.x * 256 + threadIdx.x;       // < 15360
    int kk   = t >> 10;
    int rem  = t & 1023;
    int ht   = rem >> 6;
    int lane = rem & 63;
    int q    = lane >> 4;
    int c15  = lane & 15;
    int k    = kk / 5;
    int kc   = kk - k * 5;
    int h    = ht * 16 + c15;
    int cb   = kc * 32 + q * 8;
    unsigned short v[8];
    #pragma unroll
    for (int e = 0; e < 8; ++e) {
        int c = cb + e;
        float f = (h < H_OUT && c < C_INCH) ? W[h * 450 + c * 3 + k] : 0.0f;
        v[e] = f2bf(f);
    }
    *(short8*)(Wpk + (size_t)t * 8) = *(short8*)v;
}

__global__ void __launch_bounds__(256, 4)
pcnn_mfma(const float* __restrict__ Xea, const int* __restrict__ Xmask,
          const unsigned short* __restrict__ Wpk,
          const float* __restrict__ bias, float* __restrict__ out) {
    __shared__ __align__(16) unsigned short sX[NROW * RS];   // 39216 B
    __shared__ __align__(16) float sSel[L_SEQ * 3];          // 1536 B (tot 40752)

    const int b    = blockIdx.x;
    const int hb   = blockIdx.y;
    const int tid  = threadIdx.x;
    const int wv   = tid >> 6;
    const int lane = tid & 63;
    const int q    = lane >> 4;
    const int c15  = lane & 15;
    const int mh   = wv & 1;          // m-half: l offset 64*mh
    const int nh   = wv >> 1;         // n-half: h offset 64*nh

    // ---- Fused staging: fp32 global -> bf16 LDS, one short8/thread-iter ----
    // t indexes short8s: row = t/19 (l = row-1), j = t%19 covers cols 8j..8j+7.
    // row 0 = zero halo (serves l=-1 and remapped l=128). Cols 150,151 zero.
    const float* xb = Xea + (size_t)b * (L_SEQ * C_INCH);
    #pragma unroll
    for (int it = 0; it < 10; ++it) {
        const int t = it * 256 + tid;
        if (it < 9 || t < NS8) {
            const int row = t / 19;
            const int j   = t - row * 19;
            float2 f0 = {0.f, 0.f}, f1 = {0.f, 0.f}, f2 = {0.f, 0.f}, f3 = {0.f, 0.f};
            if (row > 0) {
                const float2* src = (const float2*)(xb + (row - 1) * C_INCH + j * 8);
                f0 = src[0];
                f1 = src[1];
                f2 = src[2];
                if (j < 18) f3 = src[3];            // j=18: cols 150,151 stay 0
            }
            uint4 u;
            u.x = cvt2(f0); u.y = cvt2(f1); u.z = cvt2(f2); u.w = cvt2(f3);
            *(uint4*)(sX + (size_t)t * 8) = u;
        }
    }

    // mask -> piece selectors {0, -1e30}
    if (tid < L_SEQ) {
        int mv = Xmask[(size_t)b * L_SEQ + tid];
        sSel[tid * 3 + 0] = (mv == 1) ? 0.0f : -1e30f;
        sSel[tid * 3 + 1] = (mv == 2) ? 0.0f : -1e30f;
        sSel[tid * 3 + 2] = (mv == 3) ? 0.0f : -1e30f;
    }

    // first B frags in flight before the barrier (independent of LDS)
    const unsigned short* wp = Wpk + ((size_t)(hb * 8 + nh * 4) * 64 + lane) * 8;
    short8 bc[4], bn[4];
    #pragma unroll
    for (int nj = 0; nj < 4; ++nj)
        bc[nj] = *(const short8*)(wp + nj * 512);

    __syncthreads();

    // ---- MFMA: 15 K-chunks of 32, B double-buffered from L2 ----
    float4v acc[4][4];
    #pragma unroll
    for (int mi = 0; mi < 4; ++mi)
        #pragma unroll
        for (int nj = 0; nj < 4; ++nj)
            acc[mi][nj] = (float4v){0.f, 0.f, 0.f, 0.f};

    const unsigned short* a0p = sX + (mh * 64 + c15) * RS + q * 8;
    // l=128 halo: row mh*64+c15+mi*16+k == 129 only at (mh=1,mi=3,c15=15,k=2);
    // remap to row 0 (zeros).
    const unsigned short* a3p2 = (mh == 1 && c15 == 15) ? (a0p - 129 * RS) : a0p;

    #pragma unroll
    for (int kk = 0; kk < 15; ++kk) {
        const int k  = kk / 5;
        const int kc = kk - k * 5;
        if (kk < 14) {
            #pragma unroll
            for (int nj = 0; nj < 4; ++nj)
                bn[nj] = *(const short8*)(wp + (kk + 1) * 8192 + nj * 512);
        }
        short8 a[4];
        #pragma unroll
        for (int mi = 0; mi < 4; ++mi) {
            const unsigned short* base = (mi == 3 && k == 2) ? a3p2 : a0p;
            a[mi] = *(const short8*)(base + (mi * 16 + k) * RS + kc * 32);
        }
        #pragma unroll
        for (int mi = 0; mi < 4; ++mi)
            #pragma unroll
            for (int nj = 0; nj < 4; ++nj)
                acc[mi][nj] = __builtin_amdgcn_mfma_f32_16x16x32_bf16(
                    a[mi], bc[nj], acc[mi][nj], 0, 0, 0);
        #pragma unroll
        for (int nj = 0; nj < 4; ++nj)
            bc[nj] = bn[nj];
    }

    // ---- Epilogue: selector-add masked max (bias deferred) ----
    // C/D layout: col(h)=c15, row(l in frag)=q*4+r
    float pz[4][3];
    #pragma unroll
    for (int nj = 0; nj < 4; ++nj)
        #pragma unroll
        for (int p = 0; p < 3; ++p) pz[nj][p] = -1e30f;

    #pragma unroll
    for (int mi = 0; mi < 4; ++mi) {
        const int l0 = mh * 64 + mi * 16 + q * 4;            // mult of 4
        const float4v* sp = (const float4v*)(sSel + l0 * 3); // 48B, 16B-aligned
        const float4v s0 = sp[0], s1 = sp[1], s2 = sp[2];
        const float sl[12] = {s0.x, s0.y, s0.z, s0.w, s1.x, s1.y,
                              s1.z, s1.w, s2.x, s2.y, s2.z, s2.w};
        #pragma unroll
        for (int nj = 0; nj < 4; ++nj)
            #pragma unroll
            for (int r = 0; r < 4; ++r) {
                const float y = acc[mi][nj][r];
                pz[nj][0] = fmaxf(pz[nj][0], y + sl[r * 3 + 0]);
                pz[nj][1] = fmaxf(pz[nj][1], y + sl[r * 3 + 1]);
                pz[nj][2] = fmaxf(pz[nj][2], y + sl[r * 3 + 2]);
            }
    }

    __syncthreads();   // all sX reads done -> alias partials onto sX
    float* sP = (float*)sX;

    #pragma unroll
    for (int nj = 0; nj < 4; ++nj) {
        float p0 = pz[nj][0], p1 = pz[nj][1], p2 = pz[nj][2];
        p0 = fmaxf(p0, __shfl_xor(p0, 16, 64));
        p1 = fmaxf(p1, __shfl_xor(p1, 16, 64));
        p2 = fmaxf(p2, __shfl_xor(p2, 16, 64));
        p0 = fmaxf(p0, __shfl_xor(p0, 32, 64));
        p1 = fmaxf(p1, __shfl_xor(p1, 32, 64));
        p2 = fmaxf(p2, __shfl_xor(p2, 32, 64));
        if (q == 0) {
            const int hl = nh * 64 + nj * 16 + c15;          // 0..127
            float* d = sP + (mh * 128 + hl) * 3;
            d[0] = p0; d[1] = p1; d[2] = p2;
        }
    }
    __syncthreads();

    // Combine m-halves, add bias, clamp 0, tanh, store
    for (int t = tid; t < 384; t += 256) {
        const int hl = t / 3;
        const int p  = t - hl * 3;
        const int h  = hb * 128 + hl;
        if (h < H_OUT) {
            float v = fmaxf(sP[hl * 3 + p], sP[(128 + hl) * 3 + p]);
            v = fmaxf(0.0f, v + bias[h]);
            out[(size_t)b * (3 * H_OUT) + h * 3 + p] = tanh_fast_pos(v);
        }
    }
}

extern "C" void kernel_launch(void* const* d_in, const int* in_sizes, int n_in,
                              void* d_out, int out_size, void* d_ws, size_t ws_size,
                              hipStream_t stream) {
    const float* Xea   = (const float*)d_in[0];   // [2048,128,150] f32
    const int*   Xmask = (const int*)d_in[1];     // [2048,128] i32
    const float* W     = (const float*)d_in[2];   // [230,150,3] f32
    const float* bias  = (const float*)d_in[3];   // [230] f32
    float* out = (float*)d_out;                   // [2048,690] f32
    unsigned short* Wpk = (unsigned short*)d_ws;  // 245760 B

    pack_w_kernel<<<60, 256, 0, stream>>>(W, Wpk);
    dim3 grid(B_SZ, 2);
    pcnn_mfma<<<grid, 256, 0, stream>>>(Xea, Xmask, Wpk, bias, out);
}

// Round 8
// 279.407 us; speedup vs baseline: 1.2506x; 1.0737x over previous
//
#include <hip/hip_runtime.h>
#include <hip/hip_bf16.h>
#include <math.h>

// PCNN fused: Conv1d(k=3,pad=1) -> masked piecewise max-pool -> tanh
// R8: one block per batch element (512 threads, 8 waves = mh{0,1} x nh{0..3}),
//     X staged once per b (was twice), N=256 covered in-block.
//     K-loop / epilogue logic identical to verified R7.

#define B_SZ   2048
#define L_SEQ  128
#define C_INCH 150
#define H_OUT  230
#define RS     152      // row stride in bf16 (304 B); 152 = 19*8
#define NROW   129      // rows l=-1..127; l=128 halo remapped to row 0 (both zero)
#define NS8    2451     // short8s per tile = NROW*RS/8

typedef __attribute__((ext_vector_type(8))) short short8;   // 8 bf16
typedef __attribute__((ext_vector_type(4))) float float4v;  // mfma acc

static __device__ __forceinline__ unsigned short f2bf(float f) {
    union { float f; unsigned u; } x{f};
    unsigned r = (x.u + 0x7FFFu + ((x.u >> 16) & 1u)) >> 16;  // RNE
    return (unsigned short)r;
}

static __device__ __forceinline__ unsigned cvt2(float2 f) {
    __hip_bfloat162 h = __float22bfloat162_rn(f);   // v_cvt_pk_bf16_f32
    union { __hip_bfloat162 h; unsigned u; } c{h};
    return c.u;
}

static __device__ __forceinline__ float tanh_fast_pos(float v) {
    float e = __expf(2.0f * v);
    return 1.0f - 2.0f / (e + 1.0f);
}

// Pack W[h][c][k] fp32 -> Wpk fragment order (verified R4-R7):
//   kk = k*5+kc, ht = h/16, lane = q*16+c15
//   Wpk[((kk*16+ht)*64+lane)*8 + e] = bf16(W[ht*16+c15][kc*32+q*8+e][k])
__global__ void pack_w_kernel(const float* __restrict__ W,
                              unsigned short* __restrict__ Wpk) {
    int t = blockIdx.x * 256 + threadIdx.x;       // < 15360
    int kk   = t >> 10;
    int rem  = t & 1023;
    int ht   = rem >> 6;
    int lane = rem & 63;
    int q    = lane >> 4;
    int c15  = lane & 15;
    int k    = kk / 5;
    int kc   = kk - k * 5;
    int h    = ht * 16 + c15;
    int cb   = kc * 32 + q * 8;
    unsigned short v[8];
    #pragma unroll
    for (int e = 0; e < 8; ++e) {
        int c = cb + e;
        float f = (h < H_OUT && c < C_INCH) ? W[h * 450 + c * 3 + k] : 0.0f;
        v[e] = f2bf(f);
    }
    *(short8*)(Wpk + (size_t)t * 8) = *(short8*)v;
}

__global__ void __launch_bounds__(512, 4)
pcnn_mfma(const float* __restrict__ Xea, const int* __restrict__ Xmask,
          const unsigned short* __restrict__ Wpk,
          const float* __restrict__ bias, float* __restrict__ out) {
    __shared__ __align__(16) unsigned short sX[NROW * RS];   // 39216 B
    __shared__ __align__(16) float sSel[L_SEQ * 3];          // 1536 B (tot 40752)

    const int b    = blockIdx.x;
    const int tid  = threadIdx.x;
    const int wv   = tid >> 6;        // 0..7
    const int lane = tid & 63;
    const int q    = lane >> 4;
    const int c15  = lane & 15;
    const int mh   = wv & 1;          // m-half: l offset 64*mh
    const int nh   = wv >> 1;         // n-quarter: h offset 64*nh (0..3)

    // ---- Fused staging: fp32 global -> bf16 LDS, one short8/thread-iter ----
    // t indexes short8s: row = t/19 (l = row-1), j = t%19 covers cols 8j..8j+7.
    // row 0 = zero halo (serves l=-1 and remapped l=128). Cols 150,151 zero.
    const float* xb = Xea + (size_t)b * (L_SEQ * C_INCH);
    #pragma unroll
    for (int it = 0; it < 5; ++it) {
        const int t = it * 512 + tid;
        if (it < 4 || t < NS8) {
            const int row = t / 19;
            const int j   = t - row * 19;
            float2 f0 = {0.f, 0.f}, f1 = {0.f, 0.f}, f2 = {0.f, 0.f}, f3 = {0.f, 0.f};
            if (row > 0) {
                const float2* src = (const float2*)(xb + (row - 1) * C_INCH + j * 8);
                f0 = src[0];
                f1 = src[1];
                f2 = src[2];
                if (j < 18) f3 = src[3];            // j=18: cols 150,151 stay 0
            }
            uint4 u;
            u.x = cvt2(f0); u.y = cvt2(f1); u.z = cvt2(f2); u.w = cvt2(f3);
            *(uint4*)(sX + (size_t)t * 8) = u;
        }
    }

    // mask -> piece selectors {0, -1e30}
    if (tid < L_SEQ) {
        int mv = Xmask[(size_t)b * L_SEQ + tid];
        sSel[tid * 3 + 0] = (mv == 1) ? 0.0f : -1e30f;
        sSel[tid * 3 + 1] = (mv == 2) ? 0.0f : -1e30f;
        sSel[tid * 3 + 2] = (mv == 3) ? 0.0f : -1e30f;
    }

    // first B frags in flight before the barrier (independent of LDS)
    const unsigned short* wp = Wpk + ((size_t)(nh * 4) * 64 + lane) * 8;
    short8 bc[4], bn[4];
    #pragma unroll
    for (int nj = 0; nj < 4; ++nj)
        bc[nj] = *(const short8*)(wp + nj * 512);

    __syncthreads();

    // ---- MFMA: 15 K-chunks of 32, B double-buffered from L2 ----
    float4v acc[4][4];
    #pragma unroll
    for (int mi = 0; mi < 4; ++mi)
        #pragma unroll
        for (int nj = 0; nj < 4; ++nj)
            acc[mi][nj] = (float4v){0.f, 0.f, 0.f, 0.f};

    const unsigned short* a0p = sX + (mh * 64 + c15) * RS + q * 8;
    // l=128 halo: row mh*64+c15+mi*16+k == 129 only at (mh=1,mi=3,c15=15,k=2);
    // remap to row 0 (zeros).
    const unsigned short* a3p2 = (mh == 1 && c15 == 15) ? (a0p - 129 * RS) : a0p;

    #pragma unroll
    for (int kk = 0; kk < 15; ++kk) {
        const int k  = kk / 5;
        const int kc = kk - k * 5;
        if (kk < 14) {
            #pragma unroll
            for (int nj = 0; nj < 4; ++nj)
                bn[nj] = *(const short8*)(wp + (kk + 1) * 8192 + nj * 512);
        }
        short8 a[4];
        #pragma unroll
        for (int mi = 0; mi < 4; ++mi) {
            const unsigned short* base = (mi == 3 && k == 2) ? a3p2 : a0p;
            a[mi] = *(const short8*)(base + (mi * 16 + k) * RS + kc * 32);
        }
        #pragma unroll
        for (int mi = 0; mi < 4; ++mi)
            #pragma unroll
            for (int nj = 0; nj < 4; ++nj)
                acc[mi][nj] = __builtin_amdgcn_mfma_f32_16x16x32_bf16(
                    a[mi], bc[nj], acc[mi][nj], 0, 0, 0);
        #pragma unroll
        for (int nj = 0; nj < 4; ++nj)
            bc[nj] = bn[nj];
    }

    // ---- Epilogue: selector-add masked max (bias deferred) ----
    // C/D layout: col(h)=c15, row(l in frag)=q*4+r
    float pz[4][3];
    #pragma unroll
    for (int nj = 0; nj < 4; ++nj)
        #pragma unroll
        for (int p = 0; p < 3; ++p) pz[nj][p] = -1e30f;

    #pragma unroll
    for (int mi = 0; mi < 4; ++mi) {
        const int l0 = mh * 64 + mi * 16 + q * 4;            // mult of 4
        const float4v* sp = (const float4v*)(sSel + l0 * 3); // 48B, 16B-aligned
        const float4v s0 = sp[0], s1 = sp[1], s2 = sp[2];
        const float sl[12] = {s0.x, s0.y, s0.z, s0.w, s1.x, s1.y,
                              s1.z, s1.w, s2.x, s2.y, s2.z, s2.w};
        #pragma unroll
        for (int nj = 0; nj < 4; ++nj)
            #pragma unroll
            for (int r = 0; r < 4; ++r) {
                const float y = acc[mi][nj][r];
                pz[nj][0] = fmaxf(pz[nj][0], y + sl[r * 3 + 0]);
                pz[nj][1] = fmaxf(pz[nj][1], y + sl[r * 3 + 1]);
                pz[nj][2] = fmaxf(pz[nj][2], y + sl[r * 3 + 2]);
            }
    }

    __syncthreads();   // all sX reads done -> alias partials onto sX
    float* sP = (float*)sX;   // [mh][h 0..255][3] = 1536 floats

    #pragma unroll
    for (int nj = 0; nj < 4; ++nj) {
        float p0 = pz[nj][0], p1 = pz[nj][1], p2 = pz[nj][2];
        p0 = fmaxf(p0, __shfl_xor(p0, 16, 64));
        p1 = fmaxf(p1, __shfl_xor(p1, 16, 64));
        p2 = fmaxf(p2, __shfl_xor(p2, 16, 64));
        p0 = fmaxf(p0, __shfl_xor(p0, 32, 64));
        p1 = fmaxf(p1, __shfl_xor(p1, 32, 64));
        p2 = fmaxf(p2, __shfl_xor(p2, 32, 64));
        if (q == 0) {
            const int hl = nh * 64 + nj * 16 + c15;          // 0..255
            float* d = sP + (mh * 256 + hl) * 3;
            d[0] = p0; d[1] = p1; d[2] = p2;
        }
    }
    __syncthreads();

    // Combine m-halves, add bias, clamp 0, tanh, store
    for (int t = tid; t < 768; t += 512) {
        const int h = t / 3;
        const int p = t - h * 3;
        if (h < H_OUT) {
            float v = fmaxf(sP[h * 3 + p], sP[(256 + h) * 3 + p]);
            v = fmaxf(0.0f, v + bias[h]);
            out[(size_t)b * (3 * H_OUT) + h * 3 + p] = tanh_fast_pos(v);
        }
    }
}

extern "C" void kernel_launch(void* const* d_in, const int* in_sizes, int n_in,
                              void* d_out, int out_size, void* d_ws, size_t ws_size,
                              hipStream_t stream) {
    const float* Xea   = (const float*)d_in[0];   // [2048,128,150] f32
    const int*   Xmask = (const int*)d_in[1];     // [2048,128] i32
    const float* W     = (const float*)d_in[2];   // [230,150,3] f32
    const float* bias  = (const float*)d_in[3];   // [230] f32
    float* out = (float*)d_out;                   // [2048,690] f32
    unsigned short* Wpk = (unsigned short*)d_ws;  // 245760 B

    pack_w_kernel<<<60, 256, 0, stream>>>(W, Wpk);
    pcnn_mfma<<<B_SZ, 512, 0, stream>>>(Xea, Xmask, Wpk, bias, out);
}